// Round 4
// baseline (491.834 us; speedup 1.0000x reference)
//
#include <hip/hip_runtime.h>
#include <hip/hip_bf16.h>
#include <math.h>

// Problem shape (fixed by setup_inputs): B=128, S=20, C=32000
#define NB 128
#define NS 20
#define NC 32000
#define BPB 8             // batches per Hungarian block (one thread per batch)
#define NHB (NB / BPB)    // 16 Hungarian blocks
#define CST 404           // per-thread cost stride in floats:
                          //  - 404*4 % 16 == 0 -> rows stay 16B aligned (b128 reads)
                          //  - 404 % 32 == 20 -> the 8 solver lanes' rows land on
                          //    disjoint bank groups (20t mod 32 all distinct)

// ---------------------------------------------------------------------------
// Mega kernel, heterogeneous blocks:
//   blockIdx.x <  NHB : fused gather + restricted-softmax cost + SCALAR
//                       Hungarian. Thread t owns batch b0+t entirely; all
//                       solver state lives in LDS (no VGPR pressure, no
//                       scratch), scalars in registers, zero cross-lane ops.
//   blockIdx.x >= NHB : per-row logsumexp over C=32000 (HBM-bound stream).
// LDS/block ~19.2 KB <= 20 KB, so the 256-thread cap (8 blocks/CU) binds,
// not LDS: the HBM stream keeps full occupancy. Solver blocks (16, launched
// first) finish in ~20-40 us and hide under the ~50 us LSE stream.
// ---------------------------------------------------------------------------
__global__ __launch_bounds__(256) void mega_kernel(
        const float* __restrict__ outputs,
        const int* __restrict__ gold,
        const float* __restrict__ weight,
        int* __restrict__ match_col,     // [NB*NS] assigned 0-based column per row
        float* __restrict__ sub_ws,      // [NB*NS*NS] raw gathered logits (for final)
        float* __restrict__ logZ) {      // [NB*NS]

    if (blockIdx.x < NHB) {
        // =================== fused cost + scalar Hungarian ===================
        __shared__ float  cst[BPB * CST];        // 12,928 B: per-thread 20x20 cost
        __shared__ double u_sh[BPB][22];         //  1,408 B: row potentials
        __shared__ double v_sh[BPB][22];         //  1,408 B: col potentials
        __shared__ double minv_sh[BPB][22];      //  1,408 B
        __shared__ int    way_sh[BPB][22];       //    704 B
        __shared__ int    p_sh[BPB][22];         //    704 B
        __shared__ float  lzrow[BPB * NS];       //    640 B   (total ~19.2 KB)

        const int b0 = blockIdx.x * BPB;

        // phase 1: gather outputs[b, i, gold[b, j]] into LDS + save to ws
        for (int e = threadIdx.x; e < BPB * NS * NS; e += 256) {
            int bb = e / (NS * NS); int rem = e - bb * (NS * NS);
            int i = rem / NS; int j = rem - i * NS;
            int b = b0 + bb;
            int gc = gold[b * NS + j];
            float x = outputs[(size_t)(b * NS + i) * NC + gc];
            cst[bb * CST + i * NS + j] = x;
            sub_ws[(size_t)(b * NS + i) * NS + j] = x;
        }
        __syncthreads();
        // phase 2: per-row restricted logsumexp (BPB*NS = 160 rows)
        for (int r = threadIdx.x; r < BPB * NS; r += 256) {
            int bb = r / NS; int i = r - bb * NS;
            const float* row = &cst[bb * CST + i * NS];
            float mx = row[0];
#pragma unroll
            for (int j = 1; j < NS; ++j) mx = fmaxf(mx, row[j]);
            float s = 0.f;
#pragma unroll
            for (int j = 0; j < NS; ++j) s += __expf(row[j] - mx);
            lzrow[r] = mx + __logf(s);
        }
        __syncthreads();
        // phase 3: cost = -(x - lz) * w[gold[j]]  (BIG replaces inf), in place
        for (int e = threadIdx.x; e < BPB * NS * NS; e += 256) {
            int bb = e / (NS * NS); int rem = e - bb * (NS * NS);
            int i = rem / NS; int j = rem - i * NS;
            int b = b0 + bb;
            float w = weight[gold[b * NS + j]];
            float c = -(cst[bb * CST + i * NS + j] - lzrow[bb * NS + i]) * w;
            if (isinf(c)) c = 1e8f;
            cst[bb * CST + i * NS + j] = c;
        }
        // init solver state
        for (int e = threadIdx.x; e < BPB * 22; e += 256) {
            int bb = e / 22; int j = e - bb * 22;
            u_sh[bb][j] = 0.0;
            v_sh[bb][j] = 0.0;
            p_sh[bb][j] = 0;
            way_sh[bb][j] = 0;
        }
        __syncthreads();
        if (threadIdx.x >= BPB) return;   // only 8 solver lanes continue

        // ---- scalar shortest-augmenting-path Hungarian, one batch per lane ----
        const int t = threadIdx.x;
        const float* C = &cst[t * CST];    // [20][20], row-major i*NS+j
        double* u    = u_sh[t];            // [21], u[0] unused
        double* v    = v_sh[t];
        double* minv = minv_sh[t];
        int*    way  = way_sh[t];
        int*    p    = p_sh[t];            // p[j]: row matched to col j (0 free)
        const double DINF = (double)INFINITY;

        for (int i = 1; i <= NS; ++i) {
            int j0 = 0;
#pragma unroll
            for (int j = 1; j <= NS; ++j) minv[j] = DINF;
            unsigned usedMask = 0u;   // bit j: column j used (incl. j=0)
            unsigned actMask  = 0u;   // bit r: row r in p[used]
            while (true) {
                usedMask |= 1u << j0;
                int i0 = (j0 == 0) ? i : p[j0];
                actMask |= 1u << i0;
                double u_i0 = u[i0];
                const float* crow = &C[(i0 - 1) * NS];
                double best = DINF; int j1 = 0;
#pragma unroll
                for (int j = 1; j <= NS; ++j) {
                    if (!((usedMask >> j) & 1u)) {
                        double cur = (double)crow[j - 1] - u_i0 - v[j];
                        double mj = minv[j];
                        if (cur < mj) { mj = cur; way[j] = j0; minv[j] = cur; }
                        if (mj < best) { best = mj; j1 = j; }  // strict < => np.argmin tie-break
                    }
                }
                double delta = best;
                // u[p[used]] += delta  (exact per-iteration update, as reference)
                unsigned am = actMask;
                while (am) { int r = __ffs(am) - 1; am &= am - 1; u[r] += delta; }
#pragma unroll
                for (int j = 1; j <= NS; ++j) {
                    if ((usedMask >> j) & 1u) v[j] -= delta;
                    else                      minv[j] -= delta;
                }
                j0 = j1;
                if (p[j0] == 0) break;    // reached a free column
            }
            // augment along way[] chain
            while (j0 != 0) {
                int j1 = way[j0];
                p[j0] = (j1 == 0) ? i : p[j1];
                j0 = j1;
            }
        }
        // ans[p[j]-1] = j-1
#pragma unroll
        for (int j = 1; j <= NS; ++j) {
            match_col[(b0 + t) * NS + (p[j] - 1)] = j - 1;
        }
    } else {
        // =================== per-row logZ over C ===================
        const int row = blockIdx.x - NHB;
        const float4* rp = (const float4*)(outputs + (size_t)row * NC);
        const int n4 = NC / 4;   // 8000

        float m = -INFINITY;
        float s = 0.f;
        for (int idx = threadIdx.x; idx < n4; idx += blockDim.x) {
            float4 x = rp[idx];
            float m4 = fmaxf(fmaxf(x.x, x.y), fmaxf(x.z, x.w));
            float nm = fmaxf(m, m4);
            s = s * __expf(m - nm)
              + __expf(x.x - nm) + __expf(x.y - nm)
              + __expf(x.z - nm) + __expf(x.w - nm);
            m = nm;
        }
        for (int off = 1; off < 64; off <<= 1) {
            float om = __shfl_xor(m, off);
            float os = __shfl_xor(s, off);
            float nm = fmaxf(m, om);
            s = s * __expf(m - nm) + os * __expf(om - nm);
            m = nm;
        }
        __shared__ float smx[4], ssm[4];
        int wid = threadIdx.x >> 6;
        if ((threadIdx.x & 63) == 0) { smx[wid] = m; ssm[wid] = s; }
        __syncthreads();
        if (threadIdx.x == 0) {
            float M = smx[0], S = ssm[0];
            for (int w = 1; w < 4; ++w) {
                float om = smx[w], os = ssm[w];
                float nm = fmaxf(M, om);
                S = S * __expf(M - nm) + os * __expf(om - nm);
                M = nm;
            }
            logZ[row] = M + __logf(S);
        }
    }
}

// ---------------------------------------------------------------------------
// Final masked-mean NLL reduce — everything L2-hot (sub_ws, logZ, match_col).
// Deterministic tree reduce, f64 accumulation.
// ---------------------------------------------------------------------------
__global__ __launch_bounds__(256) void final_kernel(
        const int* __restrict__ match_col,
        const float* __restrict__ sub_ws,
        const float* __restrict__ logZ,
        const float* __restrict__ weight,
        const int* __restrict__ gold,
        const unsigned char* __restrict__ mask,
        float* __restrict__ out) {
    double nsum = 0.0, msum = 0.0;
    for (int r = threadIdx.x; r < NB * NS; r += 256) {
        int b = r / NS;
        int col = match_col[r];
        float x = sub_ws[(size_t)r * NS + col];          // outputs[b,i,match]
        float w = weight[gold[b * NS + col]];            // weight[match]
        float nll = -(x - logZ[r]) * w;
        float mk = mask[r] ? 1.f : 0.f;
        nsum += (double)(nll * mk);
        msum += (double)mk;
    }
    for (int off = 1; off < 64; off <<= 1) {
        nsum += __shfl_xor(nsum, off);
        msum += __shfl_xor(msum, off);
    }
    __shared__ double sn[4], sm[4];
    int wid = threadIdx.x >> 6;
    if ((threadIdx.x & 63) == 0) { sn[wid] = nsum; sm[wid] = msum; }
    __syncthreads();
    if (threadIdx.x == 0) {
        double N = 0.0, M = 0.0;
        for (int w = 0; w < 4; ++w) { N += sn[w]; M += sm[w]; }
        out[0] = (float)(N / (M + 1e-8));
    }
}

// ---------------------------------------------------------------------------
extern "C" void kernel_launch(void* const* d_in, const int* in_sizes, int n_in,
                              void* d_out, int out_size, void* d_ws, size_t ws_size,
                              hipStream_t stream) {
    const float* outputs        = (const float*)d_in[0];          // [B,S,C] f32
    const int*   gold           = (const int*)d_in[1];            // [B,S] i32
    const unsigned char* mask   = (const unsigned char*)d_in[2];  // [B,S] bool
    const float* weight         = (const float*)d_in[3];          // [C] f32
    float* out = (float*)d_out;

    // workspace layout
    char* ws = (char*)d_ws;
    int*   match_col = (int*)ws;                                   // NB*NS
    float* logZ      = (float*)(ws + (size_t)NB * NS * 4);         // NB*NS
    float* sub_ws    = (float*)(ws + (size_t)NB * NS * 8);         // NB*NS*NS

    mega_kernel<<<NHB + NB * NS, 256, 0, stream>>>(outputs, gold, weight,
                                                   match_col, sub_ws, logZ);
    final_kernel<<<1, 256, 0, stream>>>(match_col, sub_ws, logZ, weight, gold,
                                        mask, out);
}

// Round 5
// 76.062 us; speedup vs baseline: 6.4662x; 6.4662x over previous
//
#include <hip/hip_runtime.h>
#include <hip/hip_bf16.h>
#include <math.h>

// Problem shape (fixed by setup_inputs): B=128, S=20, C=32000
#define NB 128
#define NS 20
#define NC 32000

// ---------------------------------------------------------------------------
// Mega kernel, heterogeneous blocks:
//   blockIdx.x <  NB : fused gather + restricted-softmax cost + WAVE-PARALLEL
//                      Hungarian (lane j owns column j; f32 potentials;
//                      argmin via 5-step f32 min butterfly + ballot/ffs).
//   blockIdx.x >= NB : per-row logsumexp over C=32000 (HBM-bound stream).
// LDS/block ~1.7 KB -> thread cap (8 blocks/CU) binds; full occupancy for
// the stream. 128 solver blocks run ~30-45 us, hidden under the ~50 us LSE.
// ---------------------------------------------------------------------------
__global__ __launch_bounds__(256) void mega_kernel(
        const float* __restrict__ outputs,
        const int* __restrict__ gold,
        const float* __restrict__ weight,
        int* __restrict__ match_col,     // [NB*NS] assigned 0-based column per row
        float* __restrict__ sub_ws,      // [NB*NS*NS] raw gathered logits (for final)
        float* __restrict__ logZ) {      // [NB*NS]

    if (blockIdx.x < NB) {
        // =================== fused cost + wave Hungarian ===================
        const int b = blockIdx.x;
        const int* g = gold + b * NS;
        __shared__ float cst[NS * NS];   // sub logits, then cost, in place
        __shared__ float lzs[NS];

        // phase 1: gather outputs[b, i, gold[b, j]] (400 scattered loads) + save
        for (int e = threadIdx.x; e < NS * NS; e += 256) {
            int i = e / NS, j = e - i * NS;
            float x = outputs[(size_t)(b * NS + i) * NC + g[j]];
            cst[e] = x;
            sub_ws[(size_t)(b * NS + i) * NS + j] = x;
        }
        __syncthreads();
        // phase 2: per-row restricted logsumexp over the 20 gold columns
        if (threadIdx.x < NS) {
            int i = threadIdx.x;
            float mx = cst[i * NS];
#pragma unroll
            for (int j = 1; j < NS; ++j) mx = fmaxf(mx, cst[i * NS + j]);
            float s = 0.f;
#pragma unroll
            for (int j = 0; j < NS; ++j) s += __expf(cst[i * NS + j] - mx);
            lzs[i] = mx + __logf(s);
        }
        __syncthreads();
        // phase 3: cost = -(x - lz) * w[gold[j]]  (BIG replaces inf)
        for (int e = threadIdx.x; e < NS * NS; e += 256) {
            int i = e / NS, j = e - i * NS;
            float c = -(cst[e] - lzs[i]) * weight[g[j]];
            if (isinf(c)) c = 1e8f;
            cst[e] = c;
        }
        __syncthreads();
        if (threadIdx.x >= 64) return;   // waves 1..3 done

        // ---- wave 0: shortest-augmenting-path Hungarian, f32 potentials ----
        // Live state only in lanes 0..20 (cols) / 1..20 (rows); lanes 32..63
        // carry INF through the width-32 butterfly and are don't-care.
        const int lane = threadIdx.x;
        const float FINF = INFINITY;
        float u_r = 0.f;      // lane r (1..20): row potential
        float v_j = 0.f;      // lane j (0..20): col potential
        int p_j = 0;          // lane j: row matched to col j (0 = free)
        int way_j = 0;
        const bool is_col = (lane >= 1 && lane <= NS);

        for (int i = 1; i <= NS; ++i) {
            if (lane == 0) p_j = i;      // p[0] = i
            int j0 = 0;
            float minv_j = FINF;
            bool used_j = false;
            bool row_act = false;        // lane r: r ∈ p[used] so far
            while (true) {
                if (lane == j0) used_j = true;
                int i0 = __shfl(p_j, j0);             // 1 ds
                if (lane == i0) row_act = true;       // p[used] grows by exactly i0
                float u_i0 = __shfl(u_r, i0);         // 1 ds
                if (is_col && !used_j) {
                    float cur = cst[(i0 - 1) * NS + (lane - 1)] - u_i0 - v_j;
                    if (cur < minv_j) { minv_j = cur; way_j = j0; }  // strict <
                }
                float cand = (is_col && !used_j) ? minv_j : FINF;
                // width-32 min butterfly: 5 ds ops, no index shuffles
                float mval = cand;
#pragma unroll
                for (int off = 1; off < 32; off <<= 1)
                    mval = fminf(mval, __shfl_xor(mval, off, 32));
                // argmin index: lowest lane equal to min (np.argmin tie-break)
                unsigned long long bal = __ballot(cand == mval) & 0xFFFFFFFFull;
                int j1 = __ffsll(bal) - 1;
                float delta = mval;                   // valid on lanes 0..31
                if (row_act)     u_r += delta;        // u[p[used]] += delta
                if (used_j)      v_j -= delta;        // v[used]    -= delta
                else if (is_col) minv_j -= delta;     // minv[~used]-= delta
                j0 = j1;
                int pj0 = __shfl(p_j, j0);            // 1 ds
                if (pj0 == 0) break;                  // free column reached
            }
            // augment along way[] chain
            while (j0 != 0) {
                int j1  = __shfl(way_j, j0);
                int pj1 = __shfl(p_j, j1);
                if (lane == j0) p_j = pj1;
                j0 = j1;
            }
        }
        // ans[p[j]-1] = j-1
        if (is_col && p_j != 0) {
            match_col[b * NS + (p_j - 1)] = lane - 1;
        }
    } else {
        // =================== per-row logZ over C ===================
        const int row = blockIdx.x - NB;
        const float4* rp = (const float4*)(outputs + (size_t)row * NC);
        const int n4 = NC / 4;   // 8000

        float m = -INFINITY;
        float s = 0.f;
        for (int idx = threadIdx.x; idx < n4; idx += blockDim.x) {
            float4 x = rp[idx];
            float m4 = fmaxf(fmaxf(x.x, x.y), fmaxf(x.z, x.w));
            float nm = fmaxf(m, m4);
            s = s * __expf(m - nm)
              + __expf(x.x - nm) + __expf(x.y - nm)
              + __expf(x.z - nm) + __expf(x.w - nm);
            m = nm;
        }
        for (int off = 1; off < 64; off <<= 1) {
            float om = __shfl_xor(m, off);
            float os = __shfl_xor(s, off);
            float nm = fmaxf(m, om);
            s = s * __expf(m - nm) + os * __expf(om - nm);
            m = nm;
        }
        __shared__ float smx[4], ssm[4];
        int wid = threadIdx.x >> 6;
        if ((threadIdx.x & 63) == 0) { smx[wid] = m; ssm[wid] = s; }
        __syncthreads();
        if (threadIdx.x == 0) {
            float M = smx[0], S = ssm[0];
            for (int w = 1; w < 4; ++w) {
                float om = smx[w], os = ssm[w];
                float nm = fmaxf(M, om);
                S = S * __expf(M - nm) + os * __expf(om - nm);
                M = nm;
            }
            logZ[row] = M + __logf(S);
        }
    }
}

// ---------------------------------------------------------------------------
// Final masked-mean NLL reduce — everything L2-hot (sub_ws, logZ, match_col).
// Deterministic tree reduce, f64 accumulation.
// ---------------------------------------------------------------------------
__global__ __launch_bounds__(256) void final_kernel(
        const int* __restrict__ match_col,
        const float* __restrict__ sub_ws,
        const float* __restrict__ logZ,
        const float* __restrict__ weight,
        const int* __restrict__ gold,
        const unsigned char* __restrict__ mask,
        float* __restrict__ out) {
    double nsum = 0.0, msum = 0.0;
    for (int r = threadIdx.x; r < NB * NS; r += 256) {
        int b = r / NS;
        int col = match_col[r];
        float x = sub_ws[(size_t)r * NS + col];          // outputs[b,i,match]
        float w = weight[gold[b * NS + col]];            // weight[match]
        float nll = -(x - logZ[r]) * w;
        float mk = mask[r] ? 1.f : 0.f;
        nsum += (double)(nll * mk);
        msum += (double)mk;
    }
    for (int off = 1; off < 64; off <<= 1) {
        nsum += __shfl_xor(nsum, off);
        msum += __shfl_xor(msum, off);
    }
    __shared__ double sn[4], sm[4];
    int wid = threadIdx.x >> 6;
    if ((threadIdx.x & 63) == 0) { sn[wid] = nsum; sm[wid] = msum; }
    __syncthreads();
    if (threadIdx.x == 0) {
        double N = 0.0, M = 0.0;
        for (int w = 0; w < 4; ++w) { N += sn[w]; M += sm[w]; }
        out[0] = (float)(N / (M + 1e-8));
    }
}

// ---------------------------------------------------------------------------
extern "C" void kernel_launch(void* const* d_in, const int* in_sizes, int n_in,
                              void* d_out, int out_size, void* d_ws, size_t ws_size,
                              hipStream_t stream) {
    const float* outputs        = (const float*)d_in[0];          // [B,S,C] f32
    const int*   gold           = (const int*)d_in[1];            // [B,S] i32
    const unsigned char* mask   = (const unsigned char*)d_in[2];  // [B,S] bool
    const float* weight         = (const float*)d_in[3];          // [C] f32
    float* out = (float*)d_out;

    // workspace layout
    char* ws = (char*)d_ws;
    int*   match_col = (int*)ws;                                   // NB*NS
    float* logZ      = (float*)(ws + (size_t)NB * NS * 4);         // NB*NS
    float* sub_ws    = (float*)(ws + (size_t)NB * NS * 8);         // NB*NS*NS

    mega_kernel<<<NB + NB * NS, 256, 0, stream>>>(outputs, gold, weight,
                                                  match_col, sub_ws, logZ);
    final_kernel<<<1, 256, 0, stream>>>(match_col, sub_ws, logZ, weight, gold,
                                        mask, out);
}